// Round 6
// baseline (202.914 us; speedup 1.0000x reference)
//
#include <hip/hip_runtime.h>
#include <hip/hip_bf16.h>
#include <stdint.h>

#define Bb 128
#define Pp 4096
#define Ff 32
#define Kk 8
#define Dd 64

constexpr float EPS_ATTN_ = 1e-8f;
constexpr float EPS_LN_   = 1e-5f;
constexpr float SCALE_    = 0.125f;  // 64^-0.5

typedef __attribute__((ext_vector_type(8))) short short8;
typedef __attribute__((ext_vector_type(4))) float floatx4;
typedef __attribute__((ext_vector_type(4))) unsigned uintx4;

__device__ __forceinline__ unsigned short f2bf(float f) {
  union { float f; unsigned u; } c; c.f = f;
  unsigned u = c.u + 0x7fffu + ((c.u >> 16) & 1u);  // RNE
  return (unsigned short)(u >> 16);
}
__device__ __forceinline__ unsigned pkbf(float a, float b) {
  __hip_bfloat162 h2 = __float22bfloat162_rn(make_float2(a, b));
  union { __hip_bfloat162 h; unsigned u; } c; c.h = h2;
  return c.u;
}
__device__ __forceinline__ float wsum(float v) {
  v += __shfl_xor(v, 1, 64);  v += __shfl_xor(v, 2, 64);
  v += __shfl_xor(v, 4, 64);  v += __shfl_xor(v, 8, 64);
  v += __shfl_xor(v, 16, 64); v += __shfl_xor(v, 32, 64);
  return v;
}

// ---------------- K0: slots0 = mu+|sigma|*noise ; q~ = SCALE*(LN(slots0)@Wq^T)@Wk ; zero acc
__global__ __launch_bounds__(512) void init_kernel(
    const float* __restrict__ noise, const float* __restrict__ smu,
    const float* __restrict__ ssig, const float* __restrict__ Wq,
    const float* __restrict__ Wk,
    const float* __restrict__ lsg, const float* __restrict__ lsb,
    float* __restrict__ slots, unsigned short* __restrict__ qt_bf,
    float* __restrict__ acc_t, float* __restrict__ accs) {
  const int b = blockIdx.x;
  const int k = threadIdx.x >> 6;   // wave = slot
  const int j = threadIdx.x & 63;   // lane = d
  __shared__ float lnv[Kk][Dd];
  __shared__ float wq[64 * 65];     // Wq staged, pad 65
  __shared__ float wk[64 * 33];     // Wk staged [d][f], pad 33
  {
    const float4* g4 = (const float4*)Wq;
    #pragma unroll
    for (int i = 0; i < 2; ++i) {
      int f4i = threadIdx.x + i * 512;
      float4 v = g4[f4i];
      int fi = f4i * 4, row = fi >> 6, col = fi & 63;
      float* dst = &wq[row * 65 + col];
      dst[0] = v.x; dst[1] = v.y; dst[2] = v.z; dst[3] = v.w;
    }
    const float4* gk = (const float4*)Wk;   // 2048 floats = 512 float4
    float4 v = gk[threadIdx.x];
    int fi = threadIdx.x * 4, row = fi >> 5, col = fi & 31;
    float* dst = &wk[row * 33 + col];
    dst[0] = v.x; dst[1] = v.y; dst[2] = v.z; dst[3] = v.w;
  }
  const size_t rk = (size_t)b * Kk + k;
  float s0 = smu[j] + fabsf(ssig[j]) * noise[rk * Dd + j];
  slots[rk * Dd + j] = s0;
  float mu  = wsum(s0) * (1.f / 64.f);
  float dc  = s0 - mu;
  float var = wsum(dc * dc) * (1.f / 64.f);
  float xn  = dc * rsqrtf(var + EPS_LN_) * lsg[j] + lsb[j];
  lnv[k][j] = xn;
  __syncthreads();
  float q = 0.f;
  #pragma unroll 8
  for (int d = 0; d < Dd; ++d) q = fmaf(wq[j * 65 + d], lnv[k][d], q);
  __syncthreads();
  lnv[k][j] = q * SCALE_;          // reuse lnv for scaled q
  __syncthreads();
  if (j < Ff) {                    // q~[k][f=j] = sum_d q[d]*Wk[d][f]
    float qt = 0.f;
    #pragma unroll 8
    for (int d = 0; d < Dd; ++d) qt = fmaf(lnv[k][d], wk[d * 33 + j], qt);
    qt_bf[((size_t)b * 16 + k) * Ff + j]     = f2bf(qt);
    qt_bf[((size_t)b * 16 + k + 8) * Ff + j] = 0;   // zero rows 8..15 (MFMA M=16)
    acc_t[rk * Ff + j] = 0.f;
  }
  if (j == 0) accs[rk] = 0.f;
}

// ---------------- fused attention: direct x loads -> LN -> dots = q~ . xn^T
// -> softmax over slots -> acc_t[slot][f] += attn @ xn  (Wv applied later in gru).
#define ROUNDS 2
template <bool LAST>
__global__ __launch_bounds__(256) void fattn_kernel(
    const float* __restrict__ x, const unsigned short* __restrict__ qt_bf,
    const float* __restrict__ lg, const float* __restrict__ lb,
    float* __restrict__ acc_t, float* __restrict__ accs,
    float* __restrict__ attn_out) {
  const int b  = blockIdx.x;
  const int w    = threadIdx.x >> 6;
  const int lane = threadIdx.x & 63;
  const int m    = lane & 15;
  const int quad = lane >> 4;
  // LDS 41984 B total -> 3 blocks/CU
  __shared__ __align__(16) unsigned short xb[256 * 40];        // LN'd x, pixel-major
  __shared__ __align__(16) unsigned short xbT[32 * 264];       // LN'd x, f-major
  __shared__ __align__(16) unsigned short A_lds[4][8][72];     // attn tile (8 real slots)

  // q~ frag: A[slot=m][f=quad*8+j] (rows 8..15 are zero) — loop-invariant
  const short8 aq = *(const short8*)(qt_bf + ((size_t)b * 16 + m) * Ff + quad * 8);

  float Ss0 = 0.f, Ss1 = 0.f, Ss2 = 0.f, Ss3 = 0.f;
  floatx4 Cg0 = {0.f,0.f,0.f,0.f}, Cg1 = {0.f,0.f,0.f,0.f};

  for (int rr = 0; rr < ROUNDS; ++rr) {
    const int p0 = (blockIdx.y * ROUNDS + rr) * 256;
    if (rr) __syncthreads();   // prior round's phase-2 LDS reads complete
    // direct global load: own pixel's 32 floats (128 B contiguous per thread)
    const float4* xp = (const float4*)(x + ((size_t)b * Pp + p0 + threadIdx.x) * Ff);
    float4 xr[8];
    #pragma unroll
    for (int i = 0; i < 8; ++i) xr[i] = xp[i];
    // per-thread LN (thread = pixel) in registers
    unsigned pku[16];
    {
      float xv[Ff];
      #pragma unroll
      for (int i = 0; i < 8; ++i) {
        xv[i*4] = xr[i].x; xv[i*4+1] = xr[i].y; xv[i*4+2] = xr[i].z; xv[i*4+3] = xr[i].w;
      }
      float mu = 0.f;
      #pragma unroll
      for (int j = 0; j < Ff; ++j) mu += xv[j];
      mu *= (1.f / Ff);
      float var = 0.f;
      #pragma unroll
      for (int j = 0; j < Ff; ++j) { float d = xv[j] - mu; var = fmaf(d, d, var); }
      var *= (1.f / Ff);
      float rn = rsqrtf(var + EPS_LN_);
      #pragma unroll
      for (int j = 0; j < Ff; ++j) xv[j] = (xv[j] - mu) * rn * lg[j] + lb[j];
      #pragma unroll
      for (int p = 0; p < 16; ++p) pku[p] = pkbf(xv[2 * p], xv[2 * p + 1]);
    }
    // pixel-major copy (b128 rows, 80 B stride)
    #pragma unroll
    for (int j8 = 0; j8 < 4; ++j8)
      *(uintx4*)&xb[threadIdx.x * 40 + j8 * 8] = *(uintx4*)&pku[j8 * 4];
    // f-major copy; lane-stride-1 u16 writes = conflict-free
    #pragma unroll
    for (int p = 0; p < 16; ++p) {
      xbT[(2 * p)     * 264 + threadIdx.x] = (unsigned short)(pku[p] & 0xffffu);
      xbT[(2 * p + 1) * 264 + threadIdx.x] = (unsigned short)(pku[p] >> 16);
    }
    __syncthreads();

    // ---- phase 1: dots (1 MFMA per 16-px tile, K=F=32) + softmax over slots
    #pragma unroll
    for (int t = 0; t < 4; ++t) {
      const int lpx = w * 64 + t * 16 + m;   // local pixel for B-frag
      const short8 bx = *(const short8*)&xb[lpx * 40 + quad * 8];
      floatx4 C = {0.f, 0.f, 0.f, 0.f};
      C = __builtin_amdgcn_mfma_f32_16x16x32_bf16(aq, bx, C, 0, 0, 0);
      // C: col=m=pixel, row=quad*4+r=slot; slot pairs in lanes {l, l^16}
      float mx = fmaxf(fmaxf(C[0], C[1]), fmaxf(C[2], C[3]));
      mx = fmaxf(mx, __shfl_xor(mx, 16, 64));
      float e0 = __expf(C[0] - mx), e1 = __expf(C[1] - mx),
            e2 = __expf(C[2] - mx), e3 = __expf(C[3] - mx);
      float s = e0 + e1 + e2 + e3;
      s += __shfl_xor(s, 16, 64);
      float inv = 1.f / s;
      float a0 = fmaf(e0, inv, EPS_ATTN_), a1 = fmaf(e1, inv, EPS_ATTN_);
      float a2 = fmaf(e2, inv, EPS_ATTN_), a3 = fmaf(e3, inv, EPS_ATTN_);
      Ss0 += a0; Ss1 += a1; Ss2 += a2; Ss3 += a3;
      if (quad < 2) {                      // only rows 0..7 are real slots
        const int r0 = quad * 4;
        unsigned c01 = pkbf(a0, a1), c23 = pkbf(a2, a3);
        A_lds[w][r0 + 0][t * 16 + m] = (unsigned short)(c01 & 0xffffu);
        A_lds[w][r0 + 1][t * 16 + m] = (unsigned short)(c01 >> 16);
        A_lds[w][r0 + 2][t * 16 + m] = (unsigned short)(c23 & 0xffffu);
        A_lds[w][r0 + 3][t * 16 + m] = (unsigned short)(c23 >> 16);
        if (LAST) {
          float* ao = attn_out + ((size_t)b * Kk + r0) * Pp + p0 + w * 64 + t * 16 + m;
          ao[0] = a0; ao[Pp] = a1; ao[2 * (size_t)Pp] = a2; ao[3 * (size_t)Pp] = a3;
        }
      }
    }
    __syncthreads();
    // ---- phase 2: acc_t[slot][f] += attn @ xn  (A rows m&7; lanes 8-15 dup, C rows 8-15 unused)
    #pragma unroll
    for (int ks = 0; ks < 2; ++ks) {
      const short8 af = *(const short8*)(&A_lds[w][m & 7][ks * 32 + quad * 8]);
      const int pxo = w * 64 + ks * 32 + quad * 8;
      const short8 xg0 = *(const short8*)&xbT[(m)      * 264 + pxo];  // f = m
      const short8 xg1 = *(const short8*)&xbT[(16 + m) * 264 + pxo];  // f = 16+m
      Cg0 = __builtin_amdgcn_mfma_f32_16x16x32_bf16(af, xg0, Cg0, 0, 0, 0);
      Cg1 = __builtin_amdgcn_mfma_f32_16x16x32_bf16(af, xg1, Cg1, 0, 0, 0);
    }
  }
  // ---- epilogue (once per block)
  Ss0 += __shfl_xor(Ss0,1,64); Ss0 += __shfl_xor(Ss0,2,64); Ss0 += __shfl_xor(Ss0,4,64); Ss0 += __shfl_xor(Ss0,8,64);
  Ss1 += __shfl_xor(Ss1,1,64); Ss1 += __shfl_xor(Ss1,2,64); Ss1 += __shfl_xor(Ss1,4,64); Ss1 += __shfl_xor(Ss1,8,64);
  Ss2 += __shfl_xor(Ss2,1,64); Ss2 += __shfl_xor(Ss2,2,64); Ss2 += __shfl_xor(Ss2,4,64); Ss2 += __shfl_xor(Ss2,8,64);
  Ss3 += __shfl_xor(Ss3,1,64); Ss3 += __shfl_xor(Ss3,2,64); Ss3 += __shfl_xor(Ss3,4,64); Ss3 += __shfl_xor(Ss3,8,64);
  if (quad < 2) {
    const int row = quad * 4;
    float* tp = acc_t + ((size_t)b * Kk + row) * Ff + m;
    #pragma unroll
    for (int r = 0; r < 4; ++r) {
      atomicAdd(tp + (size_t)r * Ff,      Cg0[r]);
      atomicAdd(tp + (size_t)r * Ff + 16, Cg1[r]);
    }
    if (m == 0) {
      atomicAdd(&accs[b * Kk + row + 0], Ss0);
      atomicAdd(&accs[b * Kk + row + 1], Ss1);
      atomicAdd(&accs[b * Kk + row + 2], Ss2);
      atomicAdd(&accs[b * Kk + row + 3], Ss3);
    }
  }
}

// ---------------- G: u = (acc_t @ Wv^T)/S -> GRUCell -> +FF -> slots' ; next q~ (or f32 out)
template <bool LAST>
__global__ __launch_bounds__(256) void gru_kernel(
    const float* __restrict__ acc_t, const float* __restrict__ accs,
    float* __restrict__ slots,
    const float* __restrict__ W_ih, const float* __restrict__ W_hh,
    const float* __restrict__ b_ih, const float* __restrict__ b_hh,
    const float* __restrict__ fg, const float* __restrict__ fb,
    const float* __restrict__ W1, const float* __restrict__ b1,
    const float* __restrict__ W2, const float* __restrict__ b2,
    const float* __restrict__ lsg, const float* __restrict__ lsb,
    const float* __restrict__ Wq, const float* __restrict__ Wv,
    const float* __restrict__ Wk,
    unsigned short* __restrict__ qt_bf,
    float* __restrict__ acc_t2, float* __restrict__ accs2,
    float* __restrict__ out_slots) {
  const int b = blockIdx.x;
  const int kh = blockIdx.y;            // slot half
  const int k = threadIdx.x >> 6;       // local slot 0..3
  const int j = threadIdx.x & 63;
  const int kg = kh * 4 + k;            // global slot
  __shared__ float WA[192 * 65];        // W_ih -> then W1 (128x65) + Wq (64x65 @8320)
  __shared__ float WB[192 * 65];        // W_hh -> then W2 (64x129)
  __shared__ float WVs[64 * 33];
  __shared__ float WKs[64 * 33];
  __shared__ float At[4][Ff];
  __shared__ float Ub[4][Dd];
  __shared__ float Hb[4][Dd];
  __shared__ float Tb[4][2 * Dd];
  __shared__ float qs[4][Dd];
  {
    const float4* gi = (const float4*)W_ih;
    const float4* gh = (const float4*)W_hh;
    #pragma unroll
    for (int i = 0; i < 12; ++i) {
      int f4i = threadIdx.x + i * 256;
      float4 vi = gi[f4i], vh = gh[f4i];
      int fi = f4i * 4, row = fi >> 6, col = fi & 63;
      float* da = &WA[row * 65 + col];
      float* db = &WB[row * 65 + col];
      da[0]=vi.x; da[1]=vi.y; da[2]=vi.z; da[3]=vi.w;
      db[0]=vh.x; db[1]=vh.y; db[2]=vh.z; db[3]=vh.w;
    }
    const float4* gv = (const float4*)Wv;
    #pragma unroll
    for (int i = 0; i < 2; ++i) {
      int f4i = threadIdx.x + i * 256;
      float4 v = gv[f4i];
      int fi = f4i * 4, row = fi >> 5, col = fi & 31;
      float* d_ = &WVs[row * 33 + col];
      d_[0]=v.x; d_[1]=v.y; d_[2]=v.z; d_[3]=v.w;
    }
    if (!LAST) {
      const float4* gk = (const float4*)Wk;
      #pragma unroll
      for (int i = 0; i < 2; ++i) {
        int f4i = threadIdx.x + i * 256;
        float4 v = gk[f4i];
        int fi = f4i * 4, row = fi >> 5, col = fi & 31;
        float* d_ = &WKs[row * 33 + col];
        d_[0]=v.x; d_[1]=v.y; d_[2]=v.z; d_[3]=v.w;
      }
    }
  }
  const size_t rk = (size_t)b * Kk + kg;
  const float S = accs[rk];
  if (j < Ff) At[k][j] = acc_t[rk * Ff + j];
  const float h = slots[rk * Dd + j];
  Hb[k][j] = h;
  __syncthreads();
  // u_d = (sum_f acc_t[f] * Wv[d][f]) / S
  float u = 0.f;
  #pragma unroll 8
  for (int f = 0; f < Ff; ++f) u = fmaf(WVs[j * 33 + f], At[k][f], u);
  u /= S;
  Ub[k][j] = u;
  __syncthreads();
  float gr = b_ih[j], gz = b_ih[64 + j], gn = b_ih[128 + j];
  float hr = b_hh[j], hz = b_hh[64 + j], hn_ = b_hh[128 + j];
  #pragma unroll 4
  for (int d = 0; d < Dd; ++d) {
    const float ud = Ub[k][d], hd = Hb[k][d];
    gr  = fmaf(WA[j * 65 + d],         ud, gr);
    gz  = fmaf(WA[(64 + j) * 65 + d],  ud, gz);
    gn  = fmaf(WA[(128 + j) * 65 + d], ud, gn);
    hr  = fmaf(WB[j * 65 + d],         hd, hr);
    hz  = fmaf(WB[(64 + j) * 65 + d],  hd, hz);
    hn_ = fmaf(WB[(128 + j) * 65 + d], hd, hn_);
  }
  const float r = 1.f / (1.f + __expf(-(gr + hr)));
  const float z = 1.f / (1.f + __expf(-(gz + hz)));
  const float n = tanhf(fmaf(r, hn_, gn));
  const float hnew = fmaf(z, h - n, n);    // (1-z)*n + z*h
  float mu  = wsum(hnew) * (1.f / 64.f);
  float dc  = hnew - mu;
  float var = wsum(dc * dc) * (1.f / 64.f);
  float fi_ = dc * rsqrtf(var + EPS_LN_) * fg[j] + fb[j];
  __syncthreads();   // all reads of WA/WB/Ub done
  Ub[k][j] = fi_;
  {
    const float4* g1 = (const float4*)W1;
    #pragma unroll
    for (int i = 0; i < 8; ++i) {
      int f4i = threadIdx.x + i * 256;
      float4 v = g1[f4i];
      int fi = f4i * 4, row = fi >> 6, col = fi & 63;
      float* d_ = &WA[row * 65 + col];
      d_[0]=v.x; d_[1]=v.y; d_[2]=v.z; d_[3]=v.w;
    }
    if (!LAST) {
      const float4* gq = (const float4*)Wq;
      #pragma unroll
      for (int i = 0; i < 4; ++i) {
        int f4i = threadIdx.x + i * 256;
        float4 v = gq[f4i];
        int fi = f4i * 4, row = fi >> 6, col = fi & 63;
        float* d_ = &WA[8320 + row * 65 + col];
        d_[0]=v.x; d_[1]=v.y; d_[2]=v.z; d_[3]=v.w;
      }
    }
    const float4* g2 = (const float4*)W2;
    #pragma unroll
    for (int i = 0; i < 8; ++i) {
      int f4i = threadIdx.x + i * 256;
      float4 v = g2[f4i];
      int fi = f4i * 4, row = fi >> 7, col = fi & 127;
      float* d_ = &WB[row * 129 + col];
      d_[0]=v.x; d_[1]=v.y; d_[2]=v.z; d_[3]=v.w;
    }
  }
  __syncthreads();
  float f1a = b1[j], f1b = b1[64 + j];
  #pragma unroll 4
  for (int d = 0; d < Dd; ++d) {
    const float t = Ub[k][d];
    f1a = fmaf(WA[j * 65 + d],        t, f1a);
    f1b = fmaf(WA[(64 + j) * 65 + d], t, f1b);
  }
  f1a = fmaxf(f1a, 0.f);
  f1b = fmaxf(f1b, 0.f);
  Tb[k][j]      = f1a;
  Tb[k][64 + j] = f1b;
  __syncthreads();
  float o = b2[j];
  #pragma unroll 4
  for (int e = 0; e < 2 * Dd; ++e) o = fmaf(WB[j * 129 + e], Tb[k][e], o);
  const float sn = hnew + o;
  if (!LAST) {
    slots[rk * Dd + j] = sn;
    float mq = wsum(sn) * (1.f / 64.f);
    float dq = sn - mq;
    float vq = wsum(dq * dq) * (1.f / 64.f);
    float xq = dq * rsqrtf(vq + EPS_LN_) * lsg[j] + lsb[j];
    Ub[k][j] = xq;      // Ub reads all done before Tb barrier
    __syncthreads();
    float q = 0.f;
    #pragma unroll 8
    for (int d = 0; d < Dd; ++d) q = fmaf(WA[8320 + j * 65 + d], Ub[k][d], q);
    qs[k][j] = q * SCALE_;
    __syncthreads();
    if (j < Ff) {
      float qt = 0.f;
      #pragma unroll 8
      for (int d = 0; d < Dd; ++d) qt = fmaf(qs[k][d], WKs[d * 33 + j], qt);
      qt_bf[((size_t)b * 16 + kg) * Ff + j]     = f2bf(qt);
      qt_bf[((size_t)b * 16 + kg + 8) * Ff + j] = 0;
      acc_t2[rk * Ff + j] = 0.f;
    }
    if (j == 0) accs2[rk] = 0.f;
  } else {
    out_slots[rk * Dd + j] = sn;
  }
}

// ---------------- final: attn *= 1/S  (f32 RMW, float4)
__global__ __launch_bounds__(256) void scale_kernel(
    const float* __restrict__ accs, float* __restrict__ attn) {
  const size_t idx = ((size_t)blockIdx.x * 256 + threadIdx.x) * 4;
  const int bk = (int)(idx >> 12);
  const float inv = 1.f / accs[bk];
  float4 v = *(float4*)(attn + idx);
  v.x *= inv; v.y *= inv; v.z *= inv; v.w *= inv;
  *(float4*)(attn + idx) = v;
}

extern "C" void kernel_launch(void* const* d_in, const int* in_sizes, int n_in,
                              void* d_out, int out_size, void* d_ws, size_t ws_size,
                              hipStream_t stream) {
  const float* x      = (const float*)d_in[0];
  const float* noise  = (const float*)d_in[1];
  const float* smu    = (const float*)d_in[2];
  const float* ssig   = (const float*)d_in[3];
  const float* Wq     = (const float*)d_in[4];
  const float* Wk     = (const float*)d_in[5];
  const float* Wv     = (const float*)d_in[6];
  const float* W_ih   = (const float*)d_in[7];
  const float* W_hh   = (const float*)d_in[8];
  const float* b_ih   = (const float*)d_in[9];
  const float* b_hh   = (const float*)d_in[10];
  const float* ln_in_g = (const float*)d_in[11];
  const float* ln_in_b = (const float*)d_in[12];
  const float* ln_s_g  = (const float*)d_in[13];
  const float* ln_s_b  = (const float*)d_in[14];
  const float* ff_g   = (const float*)d_in[15];
  const float* ff_b   = (const float*)d_in[16];
  const float* W1     = (const float*)d_in[17];
  const float* b1     = (const float*)d_in[18];
  const float* W2     = (const float*)d_in[19];
  const float* b2     = (const float*)d_in[20];

  char* ws = (char*)d_ws;
  unsigned short* qt_bf = (unsigned short*)(ws);        // 131,072 B
  float* slots  = (float*)(ws + 131072);                // 262,144 B
  float* acc_t1 = (float*)(ws + 393216);                // 131,072 B
  float* accs1  = (float*)(ws + 524288);                //   4,096 B
  float* acc_t2 = (float*)(ws + 528384);                // 131,072 B
  float* accs2  = (float*)(ws + 659456);                //   4,096 B

  float* out_slots = (float*)d_out;                     // [B,K,D] f32
  float* out_attn  = out_slots + (size_t)Bb * Kk * Dd;  // [B,K,P] f32

  init_kernel<<<dim3(Bb), dim3(512), 0, stream>>>(
      noise, smu, ssig, Wq, Wk, ln_s_g, ln_s_b, slots, qt_bf, acc_t1, accs1);
  fattn_kernel<false><<<dim3(Bb, 16 / ROUNDS), dim3(256), 0, stream>>>(
      x, qt_bf, ln_in_g, ln_in_b, acc_t1, accs1, nullptr);
  gru_kernel<false><<<dim3(Bb, 2), dim3(256), 0, stream>>>(
      acc_t1, accs1, slots, W_ih, W_hh, b_ih, b_hh, ff_g, ff_b,
      W1, b1, W2, b2, ln_s_g, ln_s_b, Wq, Wv, Wk, qt_bf, acc_t2, accs2, nullptr);
  fattn_kernel<true><<<dim3(Bb, 16 / ROUNDS), dim3(256), 0, stream>>>(
      x, qt_bf, ln_in_g, ln_in_b, acc_t2, accs2, out_attn);
  gru_kernel<true><<<dim3(Bb, 2), dim3(256), 0, stream>>>(
      acc_t2, accs2, slots, W_ih, W_hh, b_ih, b_hh, ff_g, ff_b,
      W1, b1, W2, b2, ln_s_g, ln_s_b, Wq, Wv, Wk, qt_bf, acc_t2, accs2, out_slots);
  scale_kernel<<<dim3(4096), dim3(256), 0, stream>>>(accs2, out_attn);
}

// Round 8
// 197.441 us; speedup vs baseline: 1.0277x; 1.0277x over previous
//
#include <hip/hip_runtime.h>
#include <hip/hip_bf16.h>
#include <stdint.h>

#define Bb 128
#define Pp 4096
#define Ff 32
#define Kk 8
#define Dd 64

constexpr float EPS_ATTN_ = 1e-8f;
constexpr float EPS_LN_   = 1e-5f;
constexpr float SCALE_    = 0.125f;  // 64^-0.5

typedef __attribute__((ext_vector_type(8))) short short8;
typedef __attribute__((ext_vector_type(4))) float floatx4;
typedef __attribute__((ext_vector_type(4))) unsigned uintx4;

__device__ __forceinline__ unsigned short f2bf(float f) {
  union { float f; unsigned u; } c; c.f = f;
  unsigned u = c.u + 0x7fffu + ((c.u >> 16) & 1u);  // RNE
  return (unsigned short)(u >> 16);
}
__device__ __forceinline__ float bf2f(unsigned h) {
  union { float f; unsigned u; } c; c.u = h << 16;
  return c.f;
}
__device__ __forceinline__ unsigned pkbf(float a, float b) {
  __hip_bfloat162 h2 = __float22bfloat162_rn(make_float2(a, b));
  union { __hip_bfloat162 h; unsigned u; } c; c.h = h2;
  return c.u;
}
__device__ __forceinline__ float wsum(float v) {
  v += __shfl_xor(v, 1, 64);  v += __shfl_xor(v, 2, 64);
  v += __shfl_xor(v, 4, 64);  v += __shfl_xor(v, 8, 64);
  v += __shfl_xor(v, 16, 64); v += __shfl_xor(v, 32, 64);
  return v;
}

// ---------------- fused attention.
// FIRST: computes q~ = SCALE*(LN(slots0)@Wq^T)@Wk per-block (redundant, deterministic).
// Both:  x-strip -> LDS -> LN -> dots (1 MFMA/16-px tile, K=F=32) -> softmax over
//        slots -> PER-WAVE partial slices acc_tp[b][y*4+w][slot][f], Ssp[b][y*4+w][slot]
//        (plain stores, no atomics — R7 bug was 4 waves sharing one slice).
// !FIRST: also writes unnormalized attn as bf16 (halved traffic; scale pass finishes).
#define ROUNDS 2
template <bool FIRST>
__global__ __launch_bounds__(256) void fattn_kernel(
    const float* __restrict__ x, const unsigned short* __restrict__ qt_bf,
    const float* __restrict__ lg, const float* __restrict__ lb,
    const float* __restrict__ noise, const float* __restrict__ smu,
    const float* __restrict__ ssig, const float* __restrict__ Wq,
    const float* __restrict__ Wk, const float* __restrict__ lsg,
    const float* __restrict__ lsb,
    float* __restrict__ acc_tp, float* __restrict__ Ssp,
    unsigned short* __restrict__ attn_bf) {
  const int b  = blockIdx.x;
  const int w    = threadIdx.x >> 6;
  const int lane = threadIdx.x & 63;
  const int m    = lane & 15;
  const int quad = lane >> 4;
  // LDS 41984 B -> 3 blocks/CU.
  //  [0..36864)     xs: f32 x staging [256][36]       (per round: stage->LN)
  //  [0..20480)     xb: bf16 LN'd x pixel-major [256][40]   (after LN)
  //  [20480..37376) xbT: bf16 LN'd x f-major [32][264]      (after LN; aliases xs tail — synced)
  //  [37376..41984) A_lds [4][8][72]
  //  FIRST preamble (before any xs use): wq@0, wk@16640, lnv@25088, qtb@27136
  __shared__ __align__(16) char smem[41984];
  float* xs = (float*)smem;
  unsigned short* xb  = (unsigned short*)smem;
  unsigned short* xbT = (unsigned short*)(smem + 20480);
  unsigned short (*A_lds)[8][72] = (unsigned short (*)[8][72])(smem + 37376);

  short8 aq;
  if (FIRST) {
    float* wq  = (float*)smem;             // 64*65
    float* wk  = (float*)(smem + 16640);   // 64*33
    float* lnv = (float*)(smem + 25088);   // 8*64
    unsigned short* qtb = (unsigned short*)(smem + 27136);  // 16*32
    {
      const float4* g4 = (const float4*)Wq;
      #pragma unroll
      for (int i = 0; i < 4; ++i) {
        int f4i = threadIdx.x + i * 256;
        float4 v = g4[f4i];
        int fi = f4i * 4, row = fi >> 6, col = fi & 63;
        float* dst = &wq[row * 65 + col];
        dst[0] = v.x; dst[1] = v.y; dst[2] = v.z; dst[3] = v.w;
      }
      const float4* gk = (const float4*)Wk;
      #pragma unroll
      for (int i = 0; i < 2; ++i) {
        int f4i = threadIdx.x + i * 256;
        float4 v = gk[f4i];
        int fi = f4i * 4, row = fi >> 5, col = fi & 31;
        float* dst = &wk[row * 33 + col];
        dst[0] = v.x; dst[1] = v.y; dst[2] = v.z; dst[3] = v.w;
      }
    }
    // slot LN: 2 slots per wave, lane = d
    const int j = lane;
    #pragma unroll
    for (int kk0 = 0; kk0 < 2; ++kk0) {
      const int kk = w + kk0 * 4;
      float s0 = smu[j] + fabsf(ssig[j]) * noise[((size_t)b * Kk + kk) * Dd + j];
      float mu  = wsum(s0) * (1.f / 64.f);
      float dc  = s0 - mu;
      float var = wsum(dc * dc) * (1.f / 64.f);
      lnv[kk * 64 + j] = dc * rsqrtf(var + EPS_LN_) * lsg[j] + lsb[j];
    }
    __syncthreads();
    float qa = 0.f, qb = 0.f;
    #pragma unroll 8
    for (int d = 0; d < Dd; ++d) {
      float wv = wq[j * 65 + d];
      qa = fmaf(wv, lnv[w * 64 + d],       qa);
      qb = fmaf(wv, lnv[(w + 4) * 64 + d], qb);
    }
    __syncthreads();
    lnv[w * 64 + j]       = qa * SCALE_;
    lnv[(w + 4) * 64 + j] = qb * SCALE_;
    __syncthreads();
    {
      const int kq = threadIdx.x >> 5, fq = threadIdx.x & 31;
      float qt = 0.f;
      #pragma unroll 8
      for (int d = 0; d < Dd; ++d) qt = fmaf(lnv[kq * 64 + d], wk[d * 33 + fq], qt);
      qtb[kq * 32 + fq]       = f2bf(qt);
      qtb[(kq + 8) * 32 + fq] = 0;           // zero rows 8..15 (MFMA M=16)
    }
    __syncthreads();
    aq = *(const short8*)&qtb[m * 32 + quad * 8];
    __syncthreads();   // qtb reads done before xs overwrites the region
  } else {
    aq = *(const short8*)(qt_bf + ((size_t)b * 16 + m) * Ff + quad * 8);
  }

  float Ss0 = 0.f, Ss1 = 0.f, Ss2 = 0.f, Ss3 = 0.f;
  floatx4 Cg0 = {0.f,0.f,0.f,0.f}, Cg1 = {0.f,0.f,0.f,0.f};

  for (int rr = 0; rr < ROUNDS; ++rr) {
    const int p0 = (blockIdx.y * ROUNDS + rr) * 256;
    if (rr) __syncthreads();   // prior round's phase-2 LDS reads complete
    // stage x coalesced -> LDS
    {
      const float4* xg4 = (const float4*)(x + ((size_t)b * Pp + p0) * Ff);
      float4 st[8];
      #pragma unroll
      for (int i = 0; i < 8; ++i) st[i] = xg4[threadIdx.x + i * 256];
      #pragma unroll
      for (int i = 0; i < 8; ++i) {
        int f4i = threadIdx.x + i * 256;
        int px = f4i >> 3, c = (f4i & 7) * 4;
        *(float4*)&xs[px * 36 + c] = st[i];
      }
    }
    __syncthreads();
    // per-thread LN (thread = pixel) in registers
    unsigned pku[16];
    {
      float xv[Ff];
      #pragma unroll
      for (int j4 = 0; j4 < 8; ++j4) {
        float4 t = *(const float4*)&xs[threadIdx.x * 36 + j4 * 4];
        xv[j4*4] = t.x; xv[j4*4+1] = t.y; xv[j4*4+2] = t.z; xv[j4*4+3] = t.w;
      }
      float mu = 0.f;
      #pragma unroll
      for (int j = 0; j < Ff; ++j) mu += xv[j];
      mu *= (1.f / Ff);
      float var = 0.f;
      #pragma unroll
      for (int j = 0; j < Ff; ++j) { float d = xv[j] - mu; var = fmaf(d, d, var); }
      var *= (1.f / Ff);
      float rn = rsqrtf(var + EPS_LN_);
      #pragma unroll
      for (int j = 0; j < Ff; ++j) xv[j] = (xv[j] - mu) * rn * lg[j] + lb[j];
      #pragma unroll
      for (int p = 0; p < 16; ++p) pku[p] = pkbf(xv[2 * p], xv[2 * p + 1]);
    }
    __syncthreads();   // xs reads done -> safe to overwrite as xb/xbT
    #pragma unroll
    for (int j8 = 0; j8 < 4; ++j8)
      *(uintx4*)&xb[threadIdx.x * 40 + j8 * 8] = *(uintx4*)&pku[j8 * 4];
    #pragma unroll
    for (int p = 0; p < 16; ++p) {
      xbT[(2 * p)     * 264 + threadIdx.x] = (unsigned short)(pku[p] & 0xffffu);
      xbT[(2 * p + 1) * 264 + threadIdx.x] = (unsigned short)(pku[p] >> 16);
    }
    __syncthreads();

    // ---- phase 1: dots + softmax over slots
    #pragma unroll
    for (int t = 0; t < 4; ++t) {
      const int lpx = w * 64 + t * 16 + m;
      const short8 bx = *(const short8*)&xb[lpx * 40 + quad * 8];
      floatx4 C = {0.f, 0.f, 0.f, 0.f};
      C = __builtin_amdgcn_mfma_f32_16x16x32_bf16(aq, bx, C, 0, 0, 0);
      // C: col=m=pixel, row=quad*4+r=slot; slot pairs in lanes {l, l^16}
      float mx = fmaxf(fmaxf(C[0], C[1]), fmaxf(C[2], C[3]));
      mx = fmaxf(mx, __shfl_xor(mx, 16, 64));
      float e0 = __expf(C[0] - mx), e1 = __expf(C[1] - mx),
            e2 = __expf(C[2] - mx), e3 = __expf(C[3] - mx);
      float s = e0 + e1 + e2 + e3;
      s += __shfl_xor(s, 16, 64);
      float inv = 1.f / s;
      float a0 = fmaf(e0, inv, EPS_ATTN_), a1 = fmaf(e1, inv, EPS_ATTN_);
      float a2 = fmaf(e2, inv, EPS_ATTN_), a3 = fmaf(e3, inv, EPS_ATTN_);
      Ss0 += a0; Ss1 += a1; Ss2 += a2; Ss3 += a3;
      if (quad < 2) {                      // rows 0..7 are the real slots
        const int r0 = quad * 4;
        unsigned c01 = pkbf(a0, a1), c23 = pkbf(a2, a3);
        A_lds[w][r0 + 0][t * 16 + m] = (unsigned short)(c01 & 0xffffu);
        A_lds[w][r0 + 1][t * 16 + m] = (unsigned short)(c01 >> 16);
        A_lds[w][r0 + 2][t * 16 + m] = (unsigned short)(c23 & 0xffffu);
        A_lds[w][r0 + 3][t * 16 + m] = (unsigned short)(c23 >> 16);
        if (!FIRST) {
          unsigned short* ao = attn_bf + ((size_t)b * Kk + r0) * Pp + p0 + w * 64 + t * 16 + m;
          ao[0]      = (unsigned short)(c01 & 0xffffu);
          ao[Pp]     = (unsigned short)(c01 >> 16);
          ao[2 * Pp] = (unsigned short)(c23 & 0xffffu);
          ao[3 * Pp] = (unsigned short)(c23 >> 16);
        }
      }
    }
    __syncthreads();
    // ---- phase 2: acc[slot][f] += attn @ xn
    #pragma unroll
    for (int ks = 0; ks < 2; ++ks) {
      const short8 af = *(const short8*)(&A_lds[w][m & 7][ks * 32 + quad * 8]);
      const int pxo = w * 64 + ks * 32 + quad * 8;
      const short8 xg0 = *(const short8*)&xbT[(m)      * 264 + pxo];  // f = m
      const short8 xg1 = *(const short8*)&xbT[(16 + m) * 264 + pxo];  // f = 16+m
      Cg0 = __builtin_amdgcn_mfma_f32_16x16x32_bf16(af, xg0, Cg0, 0, 0, 0);
      Cg1 = __builtin_amdgcn_mfma_f32_16x16x32_bf16(af, xg1, Cg1, 0, 0, 0);
    }
  }
  // ---- epilogue: PER-WAVE private slices (slice id = blockIdx.y*4 + w)
  Ss0 += __shfl_xor(Ss0,1,64); Ss0 += __shfl_xor(Ss0,2,64); Ss0 += __shfl_xor(Ss0,4,64); Ss0 += __shfl_xor(Ss0,8,64);
  Ss1 += __shfl_xor(Ss1,1,64); Ss1 += __shfl_xor(Ss1,2,64); Ss1 += __shfl_xor(Ss1,4,64); Ss1 += __shfl_xor(Ss1,8,64);
  Ss2 += __shfl_xor(Ss2,1,64); Ss2 += __shfl_xor(Ss2,2,64); Ss2 += __shfl_xor(Ss2,4,64); Ss2 += __shfl_xor(Ss2,8,64);
  Ss3 += __shfl_xor(Ss3,1,64); Ss3 += __shfl_xor(Ss3,2,64); Ss3 += __shfl_xor(Ss3,4,64); Ss3 += __shfl_xor(Ss3,8,64);
  if (quad < 2) {
    const int row = quad * 4;
    const int slice = blockIdx.y * 4 + w;            // 0..31
    float* tp = acc_tp + (size_t)b * 8192 + (size_t)slice * 256 + (size_t)row * 32 + m;
    #pragma unroll
    for (int r = 0; r < 4; ++r) {
      tp[r * 32]      = Cg0[r];
      tp[r * 32 + 16] = Cg1[r];
    }
    if (m == 0) {
      float* sp = Ssp + ((size_t)b * 32 + slice) * 8 + row;
      sp[0] = Ss0; sp[1] = Ss1; sp[2] = Ss2; sp[3] = Ss3;
    }
  }
}

// ---------------- G: sum 32 partials -> u = (T @ Wv^T)/S -> GRUCell -> +FF -> slots'
// !LAST recomputes slots0 from noise and emits next q~.
template <bool LAST>
__global__ __launch_bounds__(256) void gru_kernel(
    const float* __restrict__ acc_tp, const float* __restrict__ Ssp,
    float* __restrict__ slots,
    const float* __restrict__ noise, const float* __restrict__ smu,
    const float* __restrict__ ssig,
    const float* __restrict__ W_ih, const float* __restrict__ W_hh,
    const float* __restrict__ b_ih, const float* __restrict__ b_hh,
    const float* __restrict__ fg, const float* __restrict__ fb,
    const float* __restrict__ W1, const float* __restrict__ b1,
    const float* __restrict__ W2, const float* __restrict__ b2,
    const float* __restrict__ lsg, const float* __restrict__ lsb,
    const float* __restrict__ Wq, const float* __restrict__ Wv,
    const float* __restrict__ Wk,
    unsigned short* __restrict__ qt_bf,
    float* __restrict__ out_slots) {
  const int b = blockIdx.x;
  const int kh = blockIdx.y;            // slot half
  const int k = threadIdx.x >> 6;       // local slot 0..3
  const int j = threadIdx.x & 63;
  const int kg = kh * 4 + k;            // global slot
  __shared__ float WA[192 * 65];        // W_ih -> then W1 (128x65) + Wq (64x65 @8320)
  __shared__ float WB[192 * 65];        // W_hh -> then W2 (64x129)
  __shared__ float WVs[64 * 33];
  __shared__ float WKs[64 * 33];
  __shared__ float At[4][Ff];
  __shared__ float Ub[4][Dd];
  __shared__ float Hb[4][Dd];
  __shared__ float Tb[4][2 * Dd];
  __shared__ float qs[4][Dd];
  {
    const float4* gi = (const float4*)W_ih;
    const float4* gh = (const float4*)W_hh;
    #pragma unroll
    for (int i = 0; i < 12; ++i) {
      int f4i = threadIdx.x + i * 256;
      float4 vi = gi[f4i], vh = gh[f4i];
      int fi = f4i * 4, row = fi >> 6, col = fi & 63;
      float* da = &WA[row * 65 + col];
      float* db = &WB[row * 65 + col];
      da[0]=vi.x; da[1]=vi.y; da[2]=vi.z; da[3]=vi.w;
      db[0]=vh.x; db[1]=vh.y; db[2]=vh.z; db[3]=vh.w;
    }
    const float4* gv = (const float4*)Wv;
    #pragma unroll
    for (int i = 0; i < 2; ++i) {
      int f4i = threadIdx.x + i * 256;
      float4 v = gv[f4i];
      int fi = f4i * 4, row = fi >> 5, col = fi & 31;
      float* d_ = &WVs[row * 33 + col];
      d_[0]=v.x; d_[1]=v.y; d_[2]=v.z; d_[3]=v.w;
    }
    if (!LAST) {
      const float4* gk = (const float4*)Wk;
      #pragma unroll
      for (int i = 0; i < 2; ++i) {
        int f4i = threadIdx.x + i * 256;
        float4 v = gk[f4i];
        int fi = f4i * 4, row = fi >> 5, col = fi & 31;
        float* d_ = &WKs[row * 33 + col];
        d_[0]=v.x; d_[1]=v.y; d_[2]=v.z; d_[3]=v.w;
      }
    }
  }
  const size_t rk = (size_t)b * Kk + kg;
  // sum the 32 per-wave partials (deterministic order)
  float S = 0.f;
  #pragma unroll
  for (int y = 0; y < 32; ++y) S += Ssp[((size_t)b * 32 + y) * 8 + kg];
  if (j < Ff) {
    const float* tp = acc_tp + (size_t)b * 8192 + (size_t)kg * 32 + j;
    float t = 0.f;
    #pragma unroll
    for (int y = 0; y < 32; ++y) t += tp[y * 256];
    At[k][j] = t;
  }
  float h;
  if (LAST) h = slots[rk * Dd + j];
  else      h = smu[j] + fabsf(ssig[j]) * noise[rk * Dd + j];  // slots0 recomputed
  Hb[k][j] = h;
  __syncthreads();
  // u_d = (sum_f T[f] * Wv[d][f]) / S
  float u = 0.f;
  #pragma unroll 8
  for (int f = 0; f < Ff; ++f) u = fmaf(WVs[j * 33 + f], At[k][f], u);
  u /= S;
  Ub[k][j] = u;
  __syncthreads();
  float gr = b_ih[j], gz = b_ih[64 + j], gn = b_ih[128 + j];
  float hr = b_hh[j], hz = b_hh[64 + j], hn_ = b_hh[128 + j];
  #pragma unroll 4
  for (int d = 0; d < Dd; ++d) {
    const float ud = Ub[k][d], hd = Hb[k][d];
    gr  = fmaf(WA[j * 65 + d],         ud, gr);
    gz  = fmaf(WA[(64 + j) * 65 + d],  ud, gz);
    gn  = fmaf(WA[(128 + j) * 65 + d], ud, gn);
    hr  = fmaf(WB[j * 65 + d],         hd, hr);
    hz  = fmaf(WB[(64 + j) * 65 + d],  hd, hz);
    hn_ = fmaf(WB[(128 + j) * 65 + d], hd, hn_);
  }
  const float r = 1.f / (1.f + __expf(-(gr + hr)));
  const float z = 1.f / (1.f + __expf(-(gz + hz)));
  const float n = tanhf(fmaf(r, hn_, gn));
  const float hnew = fmaf(z, h - n, n);    // (1-z)*n + z*h
  float mu  = wsum(hnew) * (1.f / 64.f);
  float dc  = hnew - mu;
  float var = wsum(dc * dc) * (1.f / 64.f);
  float fi_ = dc * rsqrtf(var + EPS_LN_) * fg[j] + fb[j];
  __syncthreads();   // all reads of WA/WB/Ub done
  Ub[k][j] = fi_;
  {
    const float4* g1 = (const float4*)W1;
    #pragma unroll
    for (int i = 0; i < 8; ++i) {
      int f4i = threadIdx.x + i * 256;
      float4 v = g1[f4i];
      int fi = f4i * 4, row = fi >> 6, col = fi & 63;
      float* d_ = &WA[row * 65 + col];
      d_[0]=v.x; d_[1]=v.y; d_[2]=v.z; d_[3]=v.w;
    }
    if (!LAST) {
      const float4* gq = (const float4*)Wq;
      #pragma unroll
      for (int i = 0; i < 4; ++i) {
        int f4i = threadIdx.x + i * 256;
        float4 v = gq[f4i];
        int fi = f4i * 4, row = fi >> 6, col = fi & 63;
        float* d_ = &WA[8320 + row * 65 + col];
        d_[0]=v.x; d_[1]=v.y; d_[2]=v.z; d_[3]=v.w;
      }
    }
    const float4* g2 = (const float4*)W2;
    #pragma unroll
    for (int i = 0; i < 8; ++i) {
      int f4i = threadIdx.x + i * 256;
      float4 v = g2[f4i];
      int fi = f4i * 4, row = fi >> 7, col = fi & 127;
      float* d_ = &WB[row * 129 + col];
      d_[0]=v.x; d_[1]=v.y; d_[2]=v.z; d_[3]=v.w;
    }
  }
  __syncthreads();
  float f1a = b1[j], f1b = b1[64 + j];
  #pragma unroll 4
  for (int d = 0; d < Dd; ++d) {
    const float t = Ub[k][d];
    f1a = fmaf(WA[j * 65 + d],        t, f1a);
    f1b = fmaf(WA[(64 + j) * 65 + d], t, f1b);
  }
  f1a = fmaxf(f1a, 0.f);
  f1b = fmaxf(f1b, 0.f);
  Tb[k][j]      = f1a;
  Tb[k][64 + j] = f1b;
  __syncthreads();
  float o = b2[j];
  #pragma unroll 4
  for (int e = 0; e < 2 * Dd; ++e) o = fmaf(WB[j * 129 + e], Tb[k][e], o);
  const float sn = hnew + o;
  if (!LAST) {
    slots[rk * Dd + j] = sn;
    float mq = wsum(sn) * (1.f / 64.f);
    float dq = sn - mq;
    float vq = wsum(dq * dq) * (1.f / 64.f);
    float xq = dq * rsqrtf(vq + EPS_LN_) * lsg[j] + lsb[j];
    Ub[k][j] = xq;      // Ub reads all done before Tb barrier
    __syncthreads();
    float q = 0.f;
    #pragma unroll 8
    for (int d = 0; d < Dd; ++d) q = fmaf(WA[8320 + j * 65 + d], Ub[k][d], q);
    qs[k][j] = q * SCALE_;
    __syncthreads();
    if (j < Ff) {
      float qt = 0.f;
      #pragma unroll 8
      for (int d = 0; d < Dd; ++d) qt = fmaf(qs[k][d], WKs[d * 33 + j], qt);
      qt_bf[((size_t)b * 16 + kg) * Ff + j]     = f2bf(qt);
      qt_bf[((size_t)b * 16 + kg + 8) * Ff + j] = 0;
    }
  } else {
    out_slots[rk * Dd + j] = sn;
  }
}

// ---------------- final: out_attn = bf16(attn_unnorm) * (1/S)   (bf16 read, f32 write)
__global__ __launch_bounds__(256) void scale_kernel(
    const float* __restrict__ Ssp, const unsigned short* __restrict__ attn_bf,
    float* __restrict__ out_attn) {
  const size_t idx = ((size_t)blockIdx.x * 256 + threadIdx.x) * 4;
  const int bk = (int)(idx >> 12);
  const int b = bk >> 3, k = bk & 7;
  float S = 0.f;
  #pragma unroll
  for (int y = 0; y < 32; ++y) S += Ssp[((size_t)b * 32 + y) * 8 + k];
  const float inv = 1.f / S;
  uint2 v = *(const uint2*)(attn_bf + idx);
  float4 o;
  o.x = bf2f(v.x & 0xffffu) * inv;
  o.y = bf2f(v.x >> 16)     * inv;
  o.z = bf2f(v.y & 0xffffu) * inv;
  o.w = bf2f(v.y >> 16)     * inv;
  *(float4*)(out_attn + idx) = o;
}

extern "C" void kernel_launch(void* const* d_in, const int* in_sizes, int n_in,
                              void* d_out, int out_size, void* d_ws, size_t ws_size,
                              hipStream_t stream) {
  const float* x      = (const float*)d_in[0];
  const float* noise  = (const float*)d_in[1];
  const float* smu    = (const float*)d_in[2];
  const float* ssig   = (const float*)d_in[3];
  const float* Wq     = (const float*)d_in[4];
  const float* Wk     = (const float*)d_in[5];
  const float* Wv     = (const float*)d_in[6];
  const float* W_ih   = (const float*)d_in[7];
  const float* W_hh   = (const float*)d_in[8];
  const float* b_ih   = (const float*)d_in[9];
  const float* b_hh   = (const float*)d_in[10];
  const float* ln_in_g = (const float*)d_in[11];
  const float* ln_in_b = (const float*)d_in[12];
  const float* ln_s_g  = (const float*)d_in[13];
  const float* ln_s_b  = (const float*)d_in[14];
  const float* ff_g   = (const float*)d_in[15];
  const float* ff_b   = (const float*)d_in[16];
  const float* W1     = (const float*)d_in[17];
  const float* b1     = (const float*)d_in[18];
  const float* W2     = (const float*)d_in[19];
  const float* b2     = (const float*)d_in[20];

  char* ws = (char*)d_ws;
  unsigned short* qt_bf = (unsigned short*)(ws);             //   131,072 B
  float* slots   = (float*)(ws + 131072);                    //   262,144 B
  float* acc_tp  = (float*)(ws + 393216);                    // 4,194,304 B [B][32][8][32]
  float* Ssp     = (float*)(ws + 4587520);                   //   131,072 B [B][32][8]
  unsigned short* attn_bf = (unsigned short*)(ws + 4718592); // 8,388,608 B [B][K][P]

  float* out_slots = (float*)d_out;                          // [B,K,D] f32
  float* out_attn  = out_slots + (size_t)Bb * Kk * Dd;       // [B,K,P] f32

  fattn_kernel<true><<<dim3(Bb, 8), dim3(256), 0, stream>>>(
      x, qt_bf, ln_in_g, ln_in_b, noise, smu, ssig, Wq, Wk, ln_s_g, ln_s_b,
      acc_tp, Ssp, nullptr);
  gru_kernel<false><<<dim3(Bb, 2), dim3(256), 0, stream>>>(
      acc_tp, Ssp, slots, noise, smu, ssig, W_ih, W_hh, b_ih, b_hh, ff_g, ff_b,
      W1, b1, W2, b2, ln_s_g, ln_s_b, Wq, Wv, Wk, qt_bf, nullptr);
  fattn_kernel<false><<<dim3(Bb, 8), dim3(256), 0, stream>>>(
      x, qt_bf, ln_in_g, ln_in_b, nullptr, nullptr, nullptr, nullptr, nullptr,
      nullptr, nullptr, acc_tp, Ssp, attn_bf);
  gru_kernel<true><<<dim3(Bb, 2), dim3(256), 0, stream>>>(
      acc_tp, Ssp, slots, noise, smu, ssig, W_ih, W_hh, b_ih, b_hh, ff_g, ff_b,
      W1, b1, W2, b2, ln_s_g, ln_s_b, Wq, Wv, Wk, qt_bf, out_slots);
  scale_kernel<<<dim3(4096), dim3(256), 0, stream>>>(Ssp, attn_bf, out_attn);
}